// Round 3
// baseline (472.826 us; speedup 1.0000x reference)
//
#include <hip/hip_runtime.h>
#include <hip/hip_fp16.h>
#include <math.h>

// ----------------------------------------------------------------------------
// NL-means denoise (skimage slow-mode math) + db2-wavelet sigma estimate.
// Stage 1: wavelet HH conv (stride2, symmetric pad) -> |.| -> 16384-bin hist
//          [R3: 3 channels/thread, separable row conv, 12 loads/3 outputs]
// Stage 2: single-block hist scan -> per-channel median -> sigma -> var,l2/h^2
// Stage 3: tiled NLM: per 64x32 tile, loop 169 offsets:
//          A: diff^2 (channel-sum) on 36x68 ext region -> LDS
//          B: horizontal 5-tap Gaussian conv (coeffs pre-scaled by 1/3) -> LDS
//          C: vertical 5-tap conv -> w=exp2(min(var-d,0)*log2e/h^2) -> reg acc
//          [R3: pixel tile packed as 3xfp16 in uint2 -> ds_read_b64; phase A
//           3 reads->1, phase C 12 center reads->4. R2 was LDS-issue bound
//           at ~273 cyc/wave/offset; this cuts to ~175.]
// ----------------------------------------------------------------------------

#define IMG   1024
#define HH_N  514
#define NBINS 16384
#define BIN_SCALE 4096.0f

#define TW 64
#define TH 32
#define EXTW 68          // TW+4
#define EXTH 36          // TH+4
#define NEXT (EXTH*EXTW) // 2448 diff^2 outputs
#define LROWS 48         // TH+16
#define LCOLS 80         // TW+16
#define NPIX (LROWS*LCOLS)

// Gaussian patch kernel, normalized separable taps gn = g/sum(g), g=exp(-u^2/2)
#define G0 0.05448868454910367f
#define G1 0.24420134203151178f
#define G2 0.40261994689466440f
// horizontal pass taps pre-multiplied by 1/3 (channel mean)
#define B0 0.01816289484970122f
#define B1 0.08140044734383726f
#define B2 0.13420664896488813f

#define MAD_INV 1.4826022185056018f   // 1/0.6744897501960817
#define LOG2E   1.4426950408889634f

// ---------------------------------------------------------------- stage 1
__global__ void wavelet_hist(const float* __restrict__ x, int* __restrict__ hist) {
    int idx = blockIdx.x * 256 + threadIdx.x;
    if (idx >= HH_N * HH_N) return;
    int i = idx / HH_N;
    int j = idx - i * HH_N;
    const float k4[4] = {-0.48296291314469025f, 0.8365163037378079f,
                         -0.2241438680420134f, -0.12940952255126037f};
    float acc0 = 0.f, acc1 = 0.f, acc2 = 0.f;
    const bool fast = (j >= 2 && j <= 511);
#pragma unroll
    for (int a = 0; a < 4; ++a) {
        int sy = 2 * i + a - 3;                       // 'symmetric' pad
        sy = sy < 0 ? -sy - 1 : (sy >= IMG ? 2 * IMG - 1 - sy : sy);
        const float* row = x + (size_t)sy * IMG * 3;
        float r0, r1, r2;
        if (fast) {
            const float* p = row + (2 * j - 3) * 3;   // 12 consecutive floats
            float f0 = p[0], f1 = p[1], f2 = p[2], f3 = p[3];
            float f4 = p[4], f5 = p[5], f6 = p[6], f7 = p[7];
            float f8 = p[8], f9 = p[9], f10 = p[10], f11 = p[11];
            r0 = k4[0] * f0 + k4[1] * f3 + k4[2] * f6 + k4[3] * f9;
            r1 = k4[0] * f1 + k4[1] * f4 + k4[2] * f7 + k4[3] * f10;
            r2 = k4[0] * f2 + k4[1] * f5 + k4[2] * f8 + k4[3] * f11;
        } else {
            r0 = r1 = r2 = 0.f;
#pragma unroll
            for (int b = 0; b < 4; ++b) {
                int sx = 2 * j + b - 3;
                sx = sx < 0 ? -sx - 1 : (sx >= IMG ? 2 * IMG - 1 - sx : sx);
                const float* p = row + sx * 3;
                r0 += k4[b] * p[0]; r1 += k4[b] * p[1]; r2 += k4[b] * p[2];
            }
        }
        acc0 += k4[a] * r0; acc1 += k4[a] * r1; acc2 += k4[a] * r2;
    }
    int b0 = (int)(fabsf(acc0) * BIN_SCALE); b0 = b0 > NBINS - 1 ? NBINS - 1 : b0;
    int b1 = (int)(fabsf(acc1) * BIN_SCALE); b1 = b1 > NBINS - 1 ? NBINS - 1 : b1;
    int b2 = (int)(fabsf(acc2) * BIN_SCALE); b2 = b2 > NBINS - 1 ? NBINS - 1 : b2;
    atomicAdd(&hist[b0], 1);
    atomicAdd(&hist[NBINS + b1], 1);
    atomicAdd(&hist[2 * NBINS + b2], 1);
}

// ---------------------------------------------------------------- stage 2
__global__ void sigma_scan(const int* __restrict__ hist, float* __restrict__ scal) {
    __shared__ int   sscan[1024];
    __shared__ float sres[4];   // [0]=a[k1] val, [1]=a[k2] val, [2]=sigma accum
    int t = threadIdx.x;
    for (int c = 0; c < 3; ++c) {
        const int* h = hist + c * NBINS;
        int base = t * 16;
        int s = 0;
#pragma unroll
        for (int b = 0; b < 16; ++b) s += h[base + b];
        sscan[t] = s;
        __syncthreads();
        for (int o = 1; o < 1024; o <<= 1) {            // inclusive scan
            int v = (t >= o) ? sscan[t - o] : 0;
            __syncthreads();
            sscan[t] += v;
            __syncthreads();
        }
        int cum = sscan[t] - s;                         // exclusive prefix
        // n=264196 even: median = (a[132097]+a[132098])/2 (0-based)
#pragma unroll
        for (int b = 0; b < 16; ++b) {
            int nc = cum + h[base + b];
            float v = (base + b + 0.5f) * (1.0f / BIN_SCALE);
            if (cum < 132098 && nc >= 132098) sres[0] = v;
            if (cum < 132099 && nc >= 132099) sres[1] = v;
            cum = nc;
        }
        __syncthreads();
        if (t == 0) {
            float med = 0.5f * (sres[0] + sres[1]);
            float prev = (c == 0) ? 0.f : sres[2];
            sres[2] = prev + med * MAD_INV;
        }
        __syncthreads();
    }
    if (t == 0) {
        float sigma = sres[2] * (1.0f / 3.0f);
        float hw = 0.8f * sigma;
        scal[0] = 2.0f * sigma * sigma;      // var
        scal[1] = LOG2E / (hw * hw);         // log2(e)/h^2  (for exp2f)
    }
}

// ---------------------------------------------------------------- stage 3
__device__ __forceinline__ float3 unpack_px(uint2 q) {
    __half2 h01 = *reinterpret_cast<const __half2*>(&q.x);
    float2  f01 = __half22float2(h01);
    __half2 h2  = *reinterpret_cast<const __half2*>(&q.y);
    return make_float3(f01.x, f01.y, __half2float(__low2half(h2)));
}

__launch_bounds__(512, 4)
__global__ void nlm_main(const float* __restrict__ x,
                         const float* __restrict__ scal,
                         float* __restrict__ out) {
    __shared__ __align__(16) uint2 spx[NPIX];          // packed half RGB
    __shared__ __align__(16) float sd[NEXT];           // diff^2 (ch-summed)
    __shared__ __align__(16) float sh[EXTH * TW];      // after horiz conv

    const int tid = threadIdx.x;
    const int X0 = blockIdx.x * TW;
    const int Y0 = blockIdx.y * TH;

    // --- load reflect-padded pixel tile, pack RGB -> 3xfp16 in uint2
    for (int l = tid; l < NPIX; l += 512) {
        int rr = l / LCOLS;
        int cc = l - rr * LCOLS;
        int sy = Y0 + rr - 8;                           // 'reflect' pad
        sy = sy < 0 ? -sy : (sy >= IMG ? 2 * IMG - 2 - sy : sy);
        int sc = X0 + cc - 8;
        sc = sc < 0 ? -sc : (sc >= IMG ? 2 * IMG - 2 - sc : sc);
        const float* p = x + ((size_t)sy * IMG + sc) * 3;
        uint2 u;
        u.x = (unsigned)__half_as_ushort(__float2half_rn(p[0])) |
              ((unsigned)__half_as_ushort(__float2half_rn(p[1])) << 16);
        u.y = (unsigned)__half_as_ushort(__float2half_rn(p[2]));
        spx[l] = u;
    }

    const float var  = scal[0];
    const float ih2l = scal[1];

    const int lx = tid & 63;          // output col within tile
    const int yb = (tid >> 6) * 4;    // first of 4 output rows
    float a0x = 0, a0y = 0, a0z = 0, w0s = 0;
    float a1x = 0, a1y = 0, a1z = 0, w1s = 0;
    float a2x = 0, a2y = 0, a2z = 0, w2s = 0;
    float a3x = 0, a3y = 0, a3z = 0, w3s = 0;

    __syncthreads();

    // --- register-cache the offset-invariant center values for phase A
    // thread t owns diff^2 outputs {t, t+512, ..., t+2048}
    float p10[5], p11[5], p12[5];
    int   rb[5];
#pragma unroll
    for (int k = 0; k < 5; ++k) {
        int o = tid + k * 512;
        if (o < NEXT) {
            int row = o / EXTW;
            int col = o - row * EXTW;
            rb[k] = (row + 6) * LCOLS + col + 6;
            float3 v = unpack_px(spx[rb[k]]);
            p10[k] = v.x; p11[k] = v.y; p12[k] = v.z;
        } else {
            rb[k] = 0; p10[k] = 0; p11[k] = 0; p12[k] = 0;
        }
    }

#pragma unroll 1
    for (int off = 0; off < 169; ++off) {
        const int oy = off / 13 - 6;
        const int ox = off - (off / 13) * 13 - 6;
        const int doff = oy * LCOLS + ox;

        // -------- phase A: diff^2, one output/thread, 1 b64 read each
#pragma unroll
        for (int k = 0; k < 5; ++k) {
            int o = tid + k * 512;
            if (k < 4 || o < NEXT) {
                float3 v = unpack_px(spx[rb[k] + doff]);
                float e0 = p10[k] - v.x;
                float e1 = p11[k] - v.y;
                float e2 = p12[k] - v.z;
                sd[o] = e0 * e0 + e1 * e1 + e2 * e2;
            }
        }
        __syncthreads();

        // -------- phase B: horizontal conv (taps pre-scaled by 1/3)
        for (int t = tid; t < EXTH * 16; t += 512) {
            int row = t >> 4;
            int xb4 = (t & 15) * 4;
            float4 a = *(const float4*)&sd[row * EXTW + xb4];
            float4 b = *(const float4*)&sd[row * EXTW + xb4 + 4];
            float w0 = B0 * a.x + B1 * a.y + B2 * a.z + B1 * a.w + B0 * b.x;
            float w1 = B0 * a.y + B1 * a.z + B2 * a.w + B1 * b.x + B0 * b.y;
            float w2 = B0 * a.z + B1 * a.w + B2 * b.x + B1 * b.y + B0 * b.z;
            float w3 = B0 * a.w + B1 * b.x + B2 * b.y + B1 * b.z + B0 * b.w;
            *(float4*)&sh[row * TW + xb4] = make_float4(w0, w1, w2, w3);
        }
        __syncthreads();

        // -------- phase C: vertical conv + weight + accumulate (4 rows/thread)
        {
            float s0 = sh[(yb + 0) * TW + lx];
            float s1 = sh[(yb + 1) * TW + lx];
            float s2 = sh[(yb + 2) * TW + lx];
            float s3 = sh[(yb + 3) * TW + lx];
            float s4 = sh[(yb + 4) * TW + lx];
            float s5 = sh[(yb + 5) * TW + lx];
            float s6 = sh[(yb + 6) * TW + lx];
            float s7 = sh[(yb + 7) * TW + lx];
            float d0 = G0 * s0 + G1 * s1 + G2 * s2 + G1 * s3 + G0 * s4;
            float d1 = G0 * s1 + G1 * s2 + G2 * s3 + G1 * s4 + G0 * s5;
            float d2 = G0 * s2 + G1 * s3 + G2 * s4 + G1 * s5 + G0 * s6;
            float d3 = G0 * s3 + G1 * s4 + G2 * s5 + G1 * s6 + G0 * s7;
            float w0 = exp2f(fminf(var - d0, 0.f) * ih2l);
            float w1 = exp2f(fminf(var - d1, 0.f) * ih2l);
            float w2 = exp2f(fminf(var - d2, 0.f) * ih2l);
            float w3 = exp2f(fminf(var - d3, 0.f) * ih2l);
            int cb = (yb + 8 + oy) * LCOLS + (lx + 8 + ox);
            float3 v0 = unpack_px(spx[cb]);
            float3 v1 = unpack_px(spx[cb + LCOLS]);
            float3 v2 = unpack_px(spx[cb + 2 * LCOLS]);
            float3 v3 = unpack_px(spx[cb + 3 * LCOLS]);
            a0x += w0 * v0.x; a0y += w0 * v0.y; a0z += w0 * v0.z;
            a1x += w1 * v1.x; a1y += w1 * v1.y; a1z += w1 * v1.z;
            a2x += w2 * v2.x; a2y += w2 * v2.y; a2z += w2 * v2.z;
            a3x += w3 * v3.x; a3y += w3 * v3.y; a3z += w3 * v3.z;
            w0s += w0; w1s += w1; w2s += w2; w3s += w3;
        }
        // no barrier needed: next A writes sd (readers done at bar after A->B),
        // next B writes sh only after the post-A barrier.
    }

    // -------- epilogue
    {
        int p0 = ((Y0 + yb + 0) * IMG + X0 + lx) * 3;
        int p1 = ((Y0 + yb + 1) * IMG + X0 + lx) * 3;
        int p2 = ((Y0 + yb + 2) * IMG + X0 + lx) * 3;
        int p3 = ((Y0 + yb + 3) * IMG + X0 + lx) * 3;
        float r0 = 1.f / w0s, r1 = 1.f / w1s, r2 = 1.f / w2s, r3 = 1.f / w3s;
        out[p0 + 0] = a0x * r0; out[p0 + 1] = a0y * r0; out[p0 + 2] = a0z * r0;
        out[p1 + 0] = a1x * r1; out[p1 + 1] = a1y * r1; out[p1 + 2] = a1z * r1;
        out[p2 + 0] = a2x * r2; out[p2 + 1] = a2y * r2; out[p2 + 2] = a2z * r2;
        out[p3 + 0] = a3x * r3; out[p3 + 1] = a3y * r3; out[p3 + 2] = a3z * r3;
    }
}

// ---------------------------------------------------------------- launch
extern "C" void kernel_launch(void* const* d_in, const int* in_sizes, int n_in,
                              void* d_out, int out_size, void* d_ws, size_t ws_size,
                              hipStream_t stream) {
    const float* x = (const float*)d_in[0];
    float* out = (float*)d_out;
    float* scal = (float*)d_ws;                       // [0]=var, [1]=log2e/h^2
    int* hist = (int*)((char*)d_ws + 64);             // 3*16384 ints

    hipMemsetAsync(hist, 0, 3 * NBINS * sizeof(int), stream);
    wavelet_hist<<<(HH_N * HH_N + 255) / 256, 256, 0, stream>>>(x, hist);
    sigma_scan<<<1, 1024, 0, stream>>>(hist, scal);
    dim3 grid(IMG / TW, IMG / TH);
    nlm_main<<<grid, 512, 0, stream>>>(x, scal, out);
}

// Round 4
// 467.210 us; speedup vs baseline: 1.0120x; 1.0120x over previous
//
#include <hip/hip_runtime.h>
#include <hip/hip_fp16.h>
#include <math.h>

// ----------------------------------------------------------------------------
// NL-means denoise (skimage slow-mode math) + db2-wavelet sigma estimate.
// Stage 1: wavelet HH conv (stride2, symmetric pad) -> |.| -> 16384-bin hist
// Stage 2: single-block hist scan -> per-channel median -> sigma -> var,l2/h^2
// Stage 3: tiled NLM: per 64x32 tile, loop 169 offsets:
//          A: diff^2 via packed-half pk_sub + v_dot2_f32_f16 -> LDS (fp32)
//          B: horizontal 5-tap Gaussian conv (coeffs pre-scaled by 1/3) -> LDS
//          C: vertical 5-tap conv -> w=exp2(min(var-d,0)*log2e/h^2) ->
//             v_fma_mix_f32 accumulate (fp16 pixel consumed directly)
// R4: 3 blocks/CU (launch_bounds 512,6; LDS 50KB*3<=160KB) to fill the
//     ~100us barrier-stall seen at 2 blocks/CU; phase A/C VALU trimmed
//     (R3 regression root-caused to cvt-unpack VALU, 173->210us busy).
// ----------------------------------------------------------------------------

#define IMG   1024
#define HH_N  514
#define NBINS 16384
#define BIN_SCALE 4096.0f

#define TW 64
#define TH 32
#define EXTW 68          // TW+4
#define EXTH 36          // TH+4
#define NEXT (EXTH*EXTW) // 2448 diff^2 outputs
#define LROWS 48         // TH+16
#define LCOLS 80         // TW+16
#define NPIX (LROWS*LCOLS)

// Gaussian patch kernel, normalized separable taps gn = g/sum(g), g=exp(-u^2/2)
#define G0 0.05448868454910367f
#define G1 0.24420134203151178f
#define G2 0.40261994689466440f
// horizontal pass taps pre-multiplied by 1/3 (channel mean)
#define B0 0.01816289484970122f
#define B1 0.08140044734383726f
#define B2 0.13420664896488813f

#define MAD_INV 1.4826022185056018f   // 1/0.6744897501960817
#define LOG2E   1.4426950408889634f

typedef _Float16 half2v __attribute__((ext_vector_type(2)));
union PxU { uint2 u; half2v h[2]; };

// ---------------------------------------------------------------- stage 1
__global__ void wavelet_hist(const float* __restrict__ x, int* __restrict__ hist) {
    int idx = blockIdx.x * 256 + threadIdx.x;
    if (idx >= HH_N * HH_N) return;
    int i = idx / HH_N;
    int j = idx - i * HH_N;
    const float k4[4] = {-0.48296291314469025f, 0.8365163037378079f,
                         -0.2241438680420134f, -0.12940952255126037f};
    float acc0 = 0.f, acc1 = 0.f, acc2 = 0.f;
    const bool fast = (j >= 2 && j <= 511);
#pragma unroll
    for (int a = 0; a < 4; ++a) {
        int sy = 2 * i + a - 3;                       // 'symmetric' pad
        sy = sy < 0 ? -sy - 1 : (sy >= IMG ? 2 * IMG - 1 - sy : sy);
        const float* row = x + (size_t)sy * IMG * 3;
        float r0, r1, r2;
        if (fast) {
            const float* p = row + (2 * j - 3) * 3;   // 12 consecutive floats
            float f0 = p[0], f1 = p[1], f2 = p[2], f3 = p[3];
            float f4 = p[4], f5 = p[5], f6 = p[6], f7 = p[7];
            float f8 = p[8], f9 = p[9], f10 = p[10], f11 = p[11];
            r0 = k4[0] * f0 + k4[1] * f3 + k4[2] * f6 + k4[3] * f9;
            r1 = k4[0] * f1 + k4[1] * f4 + k4[2] * f7 + k4[3] * f10;
            r2 = k4[0] * f2 + k4[1] * f5 + k4[2] * f8 + k4[3] * f11;
        } else {
            r0 = r1 = r2 = 0.f;
#pragma unroll
            for (int b = 0; b < 4; ++b) {
                int sx = 2 * j + b - 3;
                sx = sx < 0 ? -sx - 1 : (sx >= IMG ? 2 * IMG - 1 - sx : sx);
                const float* p = row + sx * 3;
                r0 += k4[b] * p[0]; r1 += k4[b] * p[1]; r2 += k4[b] * p[2];
            }
        }
        acc0 += k4[a] * r0; acc1 += k4[a] * r1; acc2 += k4[a] * r2;
    }
    int b0 = (int)(fabsf(acc0) * BIN_SCALE); b0 = b0 > NBINS - 1 ? NBINS - 1 : b0;
    int b1 = (int)(fabsf(acc1) * BIN_SCALE); b1 = b1 > NBINS - 1 ? NBINS - 1 : b1;
    int b2 = (int)(fabsf(acc2) * BIN_SCALE); b2 = b2 > NBINS - 1 ? NBINS - 1 : b2;
    atomicAdd(&hist[b0], 1);
    atomicAdd(&hist[NBINS + b1], 1);
    atomicAdd(&hist[2 * NBINS + b2], 1);
}

// ---------------------------------------------------------------- stage 2
__global__ void sigma_scan(const int* __restrict__ hist, float* __restrict__ scal) {
    __shared__ int   sscan[1024];
    __shared__ float sres[4];   // [0]=a[k1] val, [1]=a[k2] val, [2]=sigma accum
    int t = threadIdx.x;
    for (int c = 0; c < 3; ++c) {
        const int* h = hist + c * NBINS;
        int base = t * 16;
        int s = 0;
#pragma unroll
        for (int b = 0; b < 16; ++b) s += h[base + b];
        sscan[t] = s;
        __syncthreads();
        for (int o = 1; o < 1024; o <<= 1) {            // inclusive scan
            int v = (t >= o) ? sscan[t - o] : 0;
            __syncthreads();
            sscan[t] += v;
            __syncthreads();
        }
        int cum = sscan[t] - s;                         // exclusive prefix
        // n=264196 even: median = (a[132097]+a[132098])/2 (0-based)
#pragma unroll
        for (int b = 0; b < 16; ++b) {
            int nc = cum + h[base + b];
            float v = (base + b + 0.5f) * (1.0f / BIN_SCALE);
            if (cum < 132098 && nc >= 132098) sres[0] = v;
            if (cum < 132099 && nc >= 132099) sres[1] = v;
            cum = nc;
        }
        __syncthreads();
        if (t == 0) {
            float med = 0.5f * (sres[0] + sres[1]);
            float prev = (c == 0) ? 0.f : sres[2];
            sres[2] = prev + med * MAD_INV;
        }
        __syncthreads();
    }
    if (t == 0) {
        float sigma = sres[2] * (1.0f / 3.0f);
        float hw = 0.8f * sigma;
        scal[0] = 2.0f * sigma * sigma;      // var
        scal[1] = LOG2E / (hw * hw);         // log2(e)/h^2  (for exp2f)
    }
}

// ---------------------------------------------------------------- stage 3
__device__ __forceinline__ float diff2(half2v a01, half2v a2, half2v b01, half2v b2) {
#if __has_builtin(__builtin_amdgcn_fdot2)
    half2v e01 = a01 - b01;          // v_pk_add_f16 w/ neg
    half2v e2  = a2  - b2;           // high halves are 0 on both sides
    return __builtin_amdgcn_fdot2(e01, e01,
           __builtin_amdgcn_fdot2(e2, e2, 0.f, false), false);
#else
    float e0 = (float)a01[0] - (float)b01[0];
    float e1 = (float)a01[1] - (float)b01[1];
    float e2 = (float)a2[0]  - (float)b2[0];
    return e0 * e0 + e1 * e1 + e2 * e2;
#endif
}

__launch_bounds__(512, 6)
__global__ void nlm_main(const float* __restrict__ x,
                         const float* __restrict__ scal,
                         float* __restrict__ out) {
    __shared__ __align__(16) uint2 spx[NPIX];          // packed half RGB
    __shared__ __align__(16) float sd[NEXT];           // diff^2 (ch-summed)
    __shared__ __align__(16) float sh[EXTH * TW];      // after horiz conv

    const int tid = threadIdx.x;
    const int X0 = blockIdx.x * TW;
    const int Y0 = blockIdx.y * TH;

    // --- load reflect-padded pixel tile, pack RGB -> 3xfp16 in uint2
    for (int l = tid; l < NPIX; l += 512) {
        int rr = l / LCOLS;
        int cc = l - rr * LCOLS;
        int sy = Y0 + rr - 8;                           // 'reflect' pad
        sy = sy < 0 ? -sy : (sy >= IMG ? 2 * IMG - 2 - sy : sy);
        int sc = X0 + cc - 8;
        sc = sc < 0 ? -sc : (sc >= IMG ? 2 * IMG - 2 - sc : sc);
        const float* p = x + ((size_t)sy * IMG + sc) * 3;
        uint2 u;
        u.x = (unsigned)__half_as_ushort(__float2half_rn(p[0])) |
              ((unsigned)__half_as_ushort(__float2half_rn(p[1])) << 16);
        u.y = (unsigned)__half_as_ushort(__float2half_rn(p[2]));  // hi 16 = 0
        spx[l] = u;
    }

    const float var  = scal[0];
    const float ih2l = scal[1];

    const int lx = tid & 63;          // output col within tile
    const int yb = (tid >> 6) * 4;    // first of 4 output rows
    float a0x = 0, a0y = 0, a0z = 0, w0s = 0;
    float a1x = 0, a1y = 0, a1z = 0, w1s = 0;
    float a2x = 0, a2y = 0, a2z = 0, w2s = 0;
    float a3x = 0, a3y = 0, a3z = 0, w3s = 0;

    __syncthreads();

    // --- register-cache the offset-invariant center values for phase A
    // thread t owns diff^2 outputs {t, t+512, ..., t+2048}
    half2v c01[5], c2[5];
    int    rb[5];
#pragma unroll
    for (int k = 0; k < 5; ++k) {
        int o = tid + k * 512;
        if (o < NEXT) {
            int row = o / EXTW;
            int col = o - row * EXTW;
            rb[k] = (row + 6) * LCOLS + col + 6;
            PxU p; p.u = spx[rb[k]];
            c01[k] = p.h[0]; c2[k] = p.h[1];
        } else {
            rb[k] = 0; c01[k] = half2v{0, 0}; c2[k] = half2v{0, 0};
        }
    }

    int oy = -6, ox = -6;
#pragma unroll 1
    for (int off = 0; off < 169; ++off) {
        const int doff = oy * LCOLS + ox;

        // -------- phase A: diff^2, one output/thread, b64 read + dot2
#pragma unroll
        for (int k = 0; k < 5; ++k) {
            int o = tid + k * 512;
            if (k < 4 || o < NEXT) {
                PxU p; p.u = spx[rb[k] + doff];
                sd[o] = diff2(c01[k], c2[k], p.h[0], p.h[1]);
            }
        }
        __syncthreads();

        // -------- phase B: horizontal conv (taps pre-scaled by 1/3)
        for (int t = tid; t < EXTH * 16; t += 512) {
            int row = t >> 4;
            int xb4 = (t & 15) * 4;
            float4 a = *(const float4*)&sd[row * EXTW + xb4];
            float4 b = *(const float4*)&sd[row * EXTW + xb4 + 4];
            float w0 = B0 * a.x + B1 * a.y + B2 * a.z + B1 * a.w + B0 * b.x;
            float w1 = B0 * a.y + B1 * a.z + B2 * a.w + B1 * b.x + B0 * b.y;
            float w2 = B0 * a.z + B1 * a.w + B2 * b.x + B1 * b.y + B0 * b.z;
            float w3 = B0 * a.w + B1 * b.x + B2 * b.y + B1 * b.z + B0 * b.w;
            *(float4*)&sh[row * TW + xb4] = make_float4(w0, w1, w2, w3);
        }
        __syncthreads();

        // -------- phase C: vertical conv + weight + fma_mix accumulate
        {
            float s0 = sh[(yb + 0) * TW + lx];
            float s1 = sh[(yb + 1) * TW + lx];
            float s2 = sh[(yb + 2) * TW + lx];
            float s3 = sh[(yb + 3) * TW + lx];
            float s4 = sh[(yb + 4) * TW + lx];
            float s5 = sh[(yb + 5) * TW + lx];
            float s6 = sh[(yb + 6) * TW + lx];
            float s7 = sh[(yb + 7) * TW + lx];
            float d0 = G0 * s0 + G1 * s1 + G2 * s2 + G1 * s3 + G0 * s4;
            float d1 = G0 * s1 + G1 * s2 + G2 * s3 + G1 * s4 + G0 * s5;
            float d2 = G0 * s2 + G1 * s3 + G2 * s4 + G1 * s5 + G0 * s6;
            float d3 = G0 * s3 + G1 * s4 + G2 * s5 + G1 * s6 + G0 * s7;
            float w0 = exp2f(fminf(var - d0, 0.f) * ih2l);
            float w1 = exp2f(fminf(var - d1, 0.f) * ih2l);
            float w2 = exp2f(fminf(var - d2, 0.f) * ih2l);
            float w3 = exp2f(fminf(var - d3, 0.f) * ih2l);
            int cb = (yb + 8 + oy) * LCOLS + (lx + 8 + ox);
            PxU q0, q1, q2, q3;
            q0.u = spx[cb];
            q1.u = spx[cb + LCOLS];
            q2.u = spx[cb + 2 * LCOLS];
            q3.u = spx[cb + 3 * LCOLS];
            // (float)h * w + acc -> v_fma_mix_f32, no cvt
            a0x += w0 * (float)q0.h[0][0]; a0y += w0 * (float)q0.h[0][1]; a0z += w0 * (float)q0.h[1][0];
            a1x += w1 * (float)q1.h[0][0]; a1y += w1 * (float)q1.h[0][1]; a1z += w1 * (float)q1.h[1][0];
            a2x += w2 * (float)q2.h[0][0]; a2y += w2 * (float)q2.h[0][1]; a2z += w2 * (float)q2.h[1][0];
            a3x += w3 * (float)q3.h[0][0]; a3y += w3 * (float)q3.h[0][1]; a3z += w3 * (float)q3.h[1][0];
            w0s += w0; w1s += w1; w2s += w2; w3s += w3;
        }
        // no barrier needed: next A writes sd (readers done at bar after A->B),
        // next B writes sh only after the post-A barrier.
        if (++ox > 6) { ox = -6; ++oy; }
    }

    // -------- epilogue
    {
        int p0 = ((Y0 + yb + 0) * IMG + X0 + lx) * 3;
        int p1 = ((Y0 + yb + 1) * IMG + X0 + lx) * 3;
        int p2 = ((Y0 + yb + 2) * IMG + X0 + lx) * 3;
        int p3 = ((Y0 + yb + 3) * IMG + X0 + lx) * 3;
        float r0 = 1.f / w0s, r1 = 1.f / w1s, r2 = 1.f / w2s, r3 = 1.f / w3s;
        out[p0 + 0] = a0x * r0; out[p0 + 1] = a0y * r0; out[p0 + 2] = a0z * r0;
        out[p1 + 0] = a1x * r1; out[p1 + 1] = a1y * r1; out[p1 + 2] = a1z * r1;
        out[p2 + 0] = a2x * r2; out[p2 + 1] = a2y * r2; out[p2 + 2] = a2z * r2;
        out[p3 + 0] = a3x * r3; out[p3 + 1] = a3y * r3; out[p3 + 2] = a3z * r3;
    }
}

// ---------------------------------------------------------------- launch
extern "C" void kernel_launch(void* const* d_in, const int* in_sizes, int n_in,
                              void* d_out, int out_size, void* d_ws, size_t ws_size,
                              hipStream_t stream) {
    const float* x = (const float*)d_in[0];
    float* out = (float*)d_out;
    float* scal = (float*)d_ws;                       // [0]=var, [1]=log2e/h^2
    int* hist = (int*)((char*)d_ws + 64);             // 3*16384 ints

    hipMemsetAsync(hist, 0, 3 * NBINS * sizeof(int), stream);
    wavelet_hist<<<(HH_N * HH_N + 255) / 256, 256, 0, stream>>>(x, hist);
    sigma_scan<<<1, 1024, 0, stream>>>(hist, scal);
    dim3 grid(IMG / TW, IMG / TH);
    nlm_main<<<grid, 512, 0, stream>>>(x, scal, out);
}

// Round 5
// 403.180 us; speedup vs baseline: 1.1727x; 1.1588x over previous
//
#include <hip/hip_runtime.h>
#include <hip/hip_fp16.h>
#include <math.h>

// ----------------------------------------------------------------------------
// NL-means denoise (skimage slow-mode math) + db2-wavelet sigma estimate.
// Stage 1: wavelet HH conv -> |.| -> 4096-bin hist, 8 replicas (blockIdx%8)
//          [R5: replicas kill global-atomic contention (R4 profile: 40ms!)]
// Stage 2: single-block shfl-scan -> per-channel median -> sigma
//          [R5: ~12 barriers vs ~63]
// Stage 3: tiled NLM, 169 offsets: A diff^2 (pk-half dot2) -> B horiz 5-tap
//          -> C vert 5-tap + exp2 weight + fma_mix accumulate.
//          [R5: 64x16 tiles, 256 thr, 1024 blocks = 4 blocks/CU (R4 was
//           grid-limited to 2 — launch_bounds couldn't help). 4 barrier
//           domains/CU to fill the ~115us barrier-stall gap.]
// ----------------------------------------------------------------------------

#define IMG   1024
#define HH_N  514
#define NBINS 4096
#define NREP  8
#define BIN_SCALE 4096.0f

#define TW 64
#define TH 16
#define EXTW 68          // TW+4
#define EXTH 20          // TH+4
#define NEXT (EXTH*EXTW) // 1360 diff^2 outputs
#define LROWS 32         // TH+16
#define LCOLS 80         // TW+16
#define NPIX (LROWS*LCOLS)

// Gaussian patch kernel, normalized separable taps gn = g/sum(g)
#define G0 0.05448868454910367f
#define G1 0.24420134203151178f
#define G2 0.40261994689466440f
// horizontal pass taps pre-multiplied by 1/3 (channel mean)
#define B0 0.01816289484970122f
#define B1 0.08140044734383726f
#define B2 0.13420664896488813f

#define MAD_INV 1.4826022185056018f   // 1/0.6744897501960817
#define LOG2E   1.4426950408889634f

typedef _Float16 half2v __attribute__((ext_vector_type(2)));
union PxU { uint2 u; half2v h[2]; };

// ---------------------------------------------------------------- stage 1
__global__ void wavelet_hist(const float* __restrict__ x, int* __restrict__ hist) {
    int idx = blockIdx.x * 256 + threadIdx.x;
    if (idx >= HH_N * HH_N) return;
    int* hrep = hist + (blockIdx.x & (NREP - 1)) * 3 * NBINS;
    int i = idx / HH_N;
    int j = idx - i * HH_N;
    const float k4[4] = {-0.48296291314469025f, 0.8365163037378079f,
                         -0.2241438680420134f, -0.12940952255126037f};
    float acc0 = 0.f, acc1 = 0.f, acc2 = 0.f;
    const bool fast = (j >= 2 && j <= 511);
#pragma unroll
    for (int a = 0; a < 4; ++a) {
        int sy = 2 * i + a - 3;                       // 'symmetric' pad
        sy = sy < 0 ? -sy - 1 : (sy >= IMG ? 2 * IMG - 1 - sy : sy);
        const float* row = x + (size_t)sy * IMG * 3;
        float r0, r1, r2;
        if (fast) {
            const float* p = row + (2 * j - 3) * 3;   // 12 consecutive floats
            float f0 = p[0], f1 = p[1], f2 = p[2], f3 = p[3];
            float f4 = p[4], f5 = p[5], f6 = p[6], f7 = p[7];
            float f8 = p[8], f9 = p[9], f10 = p[10], f11 = p[11];
            r0 = k4[0] * f0 + k4[1] * f3 + k4[2] * f6 + k4[3] * f9;
            r1 = k4[0] * f1 + k4[1] * f4 + k4[2] * f7 + k4[3] * f10;
            r2 = k4[0] * f2 + k4[1] * f5 + k4[2] * f8 + k4[3] * f11;
        } else {
            r0 = r1 = r2 = 0.f;
#pragma unroll
            for (int b = 0; b < 4; ++b) {
                int sx = 2 * j + b - 3;
                sx = sx < 0 ? -sx - 1 : (sx >= IMG ? 2 * IMG - 1 - sx : sx);
                const float* p = row + sx * 3;
                r0 += k4[b] * p[0]; r1 += k4[b] * p[1]; r2 += k4[b] * p[2];
            }
        }
        acc0 += k4[a] * r0; acc1 += k4[a] * r1; acc2 += k4[a] * r2;
    }
    int b0 = (int)(fabsf(acc0) * BIN_SCALE); b0 = b0 > NBINS - 1 ? NBINS - 1 : b0;
    int b1 = (int)(fabsf(acc1) * BIN_SCALE); b1 = b1 > NBINS - 1 ? NBINS - 1 : b1;
    int b2 = (int)(fabsf(acc2) * BIN_SCALE); b2 = b2 > NBINS - 1 ? NBINS - 1 : b2;
    atomicAdd(&hrep[b0], 1);
    atomicAdd(&hrep[NBINS + b1], 1);
    atomicAdd(&hrep[2 * NBINS + b2], 1);
}

// ---------------------------------------------------------------- stage 2
__global__ void sigma_scan(const int* __restrict__ hist, float* __restrict__ scal) {
    __shared__ int   wsum[16];
    __shared__ float sres[4];   // [0]=a[k1], [1]=a[k2], [2]=sigma accum
    const int t = threadIdx.x;          // 1024 threads, 4096/4 bins each
    const int lane = t & 63, wid = t >> 6;
    for (int c = 0; c < 3; ++c) {
        const int* h = hist + c * NBINS;
        int cnt[4]; int tsum = 0;
#pragma unroll
        for (int b = 0; b < 4; ++b) {
            int bin = t * 4 + b, s = 0;
#pragma unroll
            for (int r = 0; r < NREP; ++r) s += h[r * 3 * NBINS + bin];
            cnt[b] = s; tsum += s;
        }
        // wave-inclusive scan of tsum
        int incl = tsum;
#pragma unroll
        for (int o = 1; o < 64; o <<= 1) {
            int v = __shfl_up(incl, o);
            if (lane >= o) incl += v;
        }
        if (lane == 63) wsum[wid] = incl;
        __syncthreads();
        if (wid == 0) {
            int v = (lane < 16) ? wsum[lane] : 0;
            int inc = v;
#pragma unroll
            for (int o = 1; o < 16; o <<= 1) {
                int u = __shfl_up(inc, o);
                if (lane >= o) inc += u;
            }
            if (lane < 16) wsum[lane] = inc - v;     // exclusive wave base
        }
        __syncthreads();
        int cum = wsum[wid] + incl - tsum;           // exclusive prefix
        // n=264196 even: median = (a[132097]+a[132098])/2 (0-based)
#pragma unroll
        for (int b = 0; b < 4; ++b) {
            int nc = cum + cnt[b];
            float v = (t * 4 + b + 0.5f) * (1.0f / BIN_SCALE);
            if (cum < 132098 && nc >= 132098) sres[0] = v;
            if (cum < 132099 && nc >= 132099) sres[1] = v;
            cum = nc;
        }
        __syncthreads();
        if (t == 0) {
            float med = 0.5f * (sres[0] + sres[1]);
            float prev = (c == 0) ? 0.f : sres[2];
            sres[2] = prev + med * MAD_INV;
        }
        __syncthreads();
    }
    if (t == 0) {
        float sigma = sres[2] * (1.0f / 3.0f);
        float hw = 0.8f * sigma;
        scal[0] = 2.0f * sigma * sigma;      // var
        scal[1] = LOG2E / (hw * hw);         // log2(e)/h^2  (for exp2f)
    }
}

// ---------------------------------------------------------------- stage 3
__device__ __forceinline__ float diff2(half2v a01, half2v a2, half2v b01, half2v b2) {
#if __has_builtin(__builtin_amdgcn_fdot2)
    half2v e01 = a01 - b01;          // v_pk_add_f16 w/ neg
    half2v e2  = a2  - b2;           // high halves are 0 on both sides
    return __builtin_amdgcn_fdot2(e01, e01,
           __builtin_amdgcn_fdot2(e2, e2, 0.f, false), false);
#else
    float e0 = (float)a01[0] - (float)b01[0];
    float e1 = (float)a01[1] - (float)b01[1];
    float e2 = (float)a2[0]  - (float)b2[0];
    return e0 * e0 + e1 * e1 + e2 * e2;
#endif
}

__launch_bounds__(256, 4)
__global__ void nlm_main(const float* __restrict__ x,
                         const float* __restrict__ scal,
                         float* __restrict__ out) {
    __shared__ __align__(16) uint2 spx[NPIX];          // packed half RGB
    __shared__ __align__(16) float sd[NEXT];           // diff^2 (ch-summed)
    __shared__ __align__(16) float sh[EXTH * TW];      // after horiz conv

    const int tid = threadIdx.x;
    const int X0 = blockIdx.x * TW;
    const int Y0 = blockIdx.y * TH;

    // --- load reflect-padded pixel tile, pack RGB -> 3xfp16 in uint2
    for (int l = tid; l < NPIX; l += 256) {
        int rr = l / LCOLS;
        int cc = l - rr * LCOLS;
        int sy = Y0 + rr - 8;                           // 'reflect' pad
        sy = sy < 0 ? -sy : (sy >= IMG ? 2 * IMG - 2 - sy : sy);
        int sc = X0 + cc - 8;
        sc = sc < 0 ? -sc : (sc >= IMG ? 2 * IMG - 2 - sc : sc);
        const float* p = x + ((size_t)sy * IMG + sc) * 3;
        uint2 u;
        u.x = (unsigned)__half_as_ushort(__float2half_rn(p[0])) |
              ((unsigned)__half_as_ushort(__float2half_rn(p[1])) << 16);
        u.y = (unsigned)__half_as_ushort(__float2half_rn(p[2]));  // hi 16 = 0
        spx[l] = u;
    }

    const float var  = scal[0];
    const float ih2l = scal[1];

    const int lx = tid & 63;          // output col within tile
    const int yb = (tid >> 6) * 4;    // first of 4 output rows
    float a0x = 0, a0y = 0, a0z = 0, w0s = 0;
    float a1x = 0, a1y = 0, a1z = 0, w1s = 0;
    float a2x = 0, a2y = 0, a2z = 0, w2s = 0;
    float a3x = 0, a3y = 0, a3z = 0, w3s = 0;

    __syncthreads();

    // --- register-cache the offset-invariant center values for phase A
    // thread t owns diff^2 outputs {t, t+256, ..., t+1280}
    half2v c01[6], c2[6];
    int    rb[6];
#pragma unroll
    for (int k = 0; k < 6; ++k) {
        int o = tid + k * 256;
        if (o < NEXT) {
            int row = o / EXTW;
            int col = o - row * EXTW;
            rb[k] = (row + 6) * LCOLS + col + 6;
            PxU p; p.u = spx[rb[k]];
            c01[k] = p.h[0]; c2[k] = p.h[1];
        } else {
            rb[k] = 0; c01[k] = half2v{0, 0}; c2[k] = half2v{0, 0};
        }
    }

    int oy = -6, ox = -6;
#pragma unroll 1
    for (int off = 0; off < 169; ++off) {
        const int doff = oy * LCOLS + ox;

        // -------- phase A: diff^2, one output/thread, b64 read + dot2
#pragma unroll
        for (int k = 0; k < 6; ++k) {
            int o = tid + k * 256;
            if (k < 5 || o < NEXT) {
                PxU p; p.u = spx[rb[k] + doff];
                sd[o] = diff2(c01[k], c2[k], p.h[0], p.h[1]);
            }
        }
        __syncthreads();

        // -------- phase B: horizontal conv (taps pre-scaled by 1/3)
        for (int t = tid; t < EXTH * 16; t += 256) {
            int row = t >> 4;
            int xb4 = (t & 15) * 4;
            float4 a = *(const float4*)&sd[row * EXTW + xb4];
            float4 b = *(const float4*)&sd[row * EXTW + xb4 + 4];
            float w0 = B0 * a.x + B1 * a.y + B2 * a.z + B1 * a.w + B0 * b.x;
            float w1 = B0 * a.y + B1 * a.z + B2 * a.w + B1 * b.x + B0 * b.y;
            float w2 = B0 * a.z + B1 * a.w + B2 * b.x + B1 * b.y + B0 * b.z;
            float w3 = B0 * a.w + B1 * b.x + B2 * b.y + B1 * b.z + B0 * b.w;
            *(float4*)&sh[row * TW + xb4] = make_float4(w0, w1, w2, w3);
        }
        __syncthreads();

        // -------- phase C: vertical conv + weight + fma_mix accumulate
        {
            float s0 = sh[(yb + 0) * TW + lx];
            float s1 = sh[(yb + 1) * TW + lx];
            float s2 = sh[(yb + 2) * TW + lx];
            float s3 = sh[(yb + 3) * TW + lx];
            float s4 = sh[(yb + 4) * TW + lx];
            float s5 = sh[(yb + 5) * TW + lx];
            float s6 = sh[(yb + 6) * TW + lx];
            float s7 = sh[(yb + 7) * TW + lx];
            float d0 = G0 * s0 + G1 * s1 + G2 * s2 + G1 * s3 + G0 * s4;
            float d1 = G0 * s1 + G1 * s2 + G2 * s3 + G1 * s4 + G0 * s5;
            float d2 = G0 * s2 + G1 * s3 + G2 * s4 + G1 * s5 + G0 * s6;
            float d3 = G0 * s3 + G1 * s4 + G2 * s5 + G1 * s6 + G0 * s7;
            float w0 = exp2f(fminf(var - d0, 0.f) * ih2l);
            float w1 = exp2f(fminf(var - d1, 0.f) * ih2l);
            float w2 = exp2f(fminf(var - d2, 0.f) * ih2l);
            float w3 = exp2f(fminf(var - d3, 0.f) * ih2l);
            int cb = (yb + 8 + oy) * LCOLS + (lx + 8 + ox);
            PxU q0, q1, q2, q3;
            q0.u = spx[cb];
            q1.u = spx[cb + LCOLS];
            q2.u = spx[cb + 2 * LCOLS];
            q3.u = spx[cb + 3 * LCOLS];
            // (float)h * w + acc -> v_fma_mix_f32, no cvt
            a0x += w0 * (float)q0.h[0][0]; a0y += w0 * (float)q0.h[0][1]; a0z += w0 * (float)q0.h[1][0];
            a1x += w1 * (float)q1.h[0][0]; a1y += w1 * (float)q1.h[0][1]; a1z += w1 * (float)q1.h[1][0];
            a2x += w2 * (float)q2.h[0][0]; a2y += w2 * (float)q2.h[0][1]; a2z += w2 * (float)q2.h[1][0];
            a3x += w3 * (float)q3.h[0][0]; a3y += w3 * (float)q3.h[0][1]; a3z += w3 * (float)q3.h[1][0];
            w0s += w0; w1s += w1; w2s += w2; w3s += w3;
        }
        // no barrier needed: next A writes sd (readers done at bar after A->B),
        // next B writes sh only after the post-A barrier.
        if (++ox > 6) { ox = -6; ++oy; }
    }

    // -------- epilogue
    {
        int p0 = ((Y0 + yb + 0) * IMG + X0 + lx) * 3;
        int p1 = ((Y0 + yb + 1) * IMG + X0 + lx) * 3;
        int p2 = ((Y0 + yb + 2) * IMG + X0 + lx) * 3;
        int p3 = ((Y0 + yb + 3) * IMG + X0 + lx) * 3;
        float r0 = 1.f / w0s, r1 = 1.f / w1s, r2 = 1.f / w2s, r3 = 1.f / w3s;
        out[p0 + 0] = a0x * r0; out[p0 + 1] = a0y * r0; out[p0 + 2] = a0z * r0;
        out[p1 + 0] = a1x * r1; out[p1 + 1] = a1y * r1; out[p1 + 2] = a1z * r1;
        out[p2 + 0] = a2x * r2; out[p2 + 1] = a2y * r2; out[p2 + 2] = a2z * r2;
        out[p3 + 0] = a3x * r3; out[p3 + 1] = a3y * r3; out[p3 + 2] = a3z * r3;
    }
}

// ---------------------------------------------------------------- launch
extern "C" void kernel_launch(void* const* d_in, const int* in_sizes, int n_in,
                              void* d_out, int out_size, void* d_ws, size_t ws_size,
                              hipStream_t stream) {
    const float* x = (const float*)d_in[0];
    float* out = (float*)d_out;
    float* scal = (float*)d_ws;                       // [0]=var, [1]=log2e/h^2
    int* hist = (int*)((char*)d_ws + 64);             // 8 reps x 3 x 4096 ints

    hipMemsetAsync(hist, 0, NREP * 3 * NBINS * sizeof(int), stream);
    wavelet_hist<<<(HH_N * HH_N + 255) / 256, 256, 0, stream>>>(x, hist);
    sigma_scan<<<1, 1024, 0, stream>>>(hist, scal);
    dim3 grid(IMG / TW, IMG / TH);
    nlm_main<<<grid, 256, 0, stream>>>(x, scal, out);
}

// Round 7
// 335.921 us; speedup vs baseline: 1.4076x; 1.2002x over previous
//
#include <hip/hip_runtime.h>
#include <hip/hip_fp16.h>
#include <math.h>

// ----------------------------------------------------------------------------
// NL-means denoise (skimage slow-mode math) + db2-wavelet sigma estimate.
// Stage 1: wavelet HH conv -> |.| -> 4096-bin hist, 4 replicas (blockIdx%4)
// Stage 2: single-block shfl-scan -> per-channel median -> sigma
// Stage 3: tiled NLM. R5 post-mortem: LDS-issue bound (786 cyc/block/offset
//          model matched 303us). R6: process offset PAIRS packed as half2 —
//          one diff^2 write, one packed pk_fma conv pass, one packed sh-read
//          pass for 2 offsets => ~1089 cyc/pair vs 1572 (-31%). Offset (0,0)
//          handled analytically (w=1). 84 pairs cover the other 168 offsets.
// R7: fix cvt_pkrtz return-type mismatch via __builtin_bit_cast.
// ----------------------------------------------------------------------------

#define IMG   1024
#define HH_N  514
#define NBINS 4096
#define NREP  4
#define BIN_SCALE 4096.0f

#define TW 64
#define TH 16
#define EXTW 68          // TW+4
#define EXTH 20          // TH+4
#define NEXT (EXTH*EXTW) // 1360 diff^2 outputs
#define LROWS 32         // TH+16
#define LCOLS 80         // TW+16
#define NPIX (LROWS*LCOLS)

// Gaussian patch kernel, normalized separable taps gn = g/sum(g)
#define G0 0.05448868454910367f
#define G1 0.24420134203151178f
#define G2 0.40261994689466440f
// horizontal pass taps pre-multiplied by 1/3 (channel mean)
#define B0 0.01816289484970122f
#define B1 0.08140044734383726f
#define B2 0.13420664896488813f

#define MAD_INV 1.4826022185056018f   // 1/0.6744897501960817
#define LOG2E   1.4426950408889634f

typedef _Float16 half2v __attribute__((ext_vector_type(2)));
union PxU { uint2 u; half2v h[2]; };
union Q4  { uint4 u; half2v h[4]; };
#define H2(x) half2v{(_Float16)(x), (_Float16)(x)}

// ---------------------------------------------------------------- stage 1
__global__ void wavelet_hist(const float* __restrict__ x, int* __restrict__ hist) {
    int idx = blockIdx.x * 256 + threadIdx.x;
    if (idx >= HH_N * HH_N) return;
    int* hrep = hist + (blockIdx.x & (NREP - 1)) * 3 * NBINS;
    int i = idx / HH_N;
    int j = idx - i * HH_N;
    const float k4[4] = {-0.48296291314469025f, 0.8365163037378079f,
                         -0.2241438680420134f, -0.12940952255126037f};
    float acc0 = 0.f, acc1 = 0.f, acc2 = 0.f;
    const bool fast = (j >= 2 && j <= 511);
#pragma unroll
    for (int a = 0; a < 4; ++a) {
        int sy = 2 * i + a - 3;                       // 'symmetric' pad
        sy = sy < 0 ? -sy - 1 : (sy >= IMG ? 2 * IMG - 1 - sy : sy);
        const float* row = x + (size_t)sy * IMG * 3;
        float r0, r1, r2;
        if (fast) {
            const float* p = row + (2 * j - 3) * 3;   // 12 consecutive floats
            float f0 = p[0], f1 = p[1], f2 = p[2], f3 = p[3];
            float f4 = p[4], f5 = p[5], f6 = p[6], f7 = p[7];
            float f8 = p[8], f9 = p[9], f10 = p[10], f11 = p[11];
            r0 = k4[0] * f0 + k4[1] * f3 + k4[2] * f6 + k4[3] * f9;
            r1 = k4[0] * f1 + k4[1] * f4 + k4[2] * f7 + k4[3] * f10;
            r2 = k4[0] * f2 + k4[1] * f5 + k4[2] * f8 + k4[3] * f11;
        } else {
            r0 = r1 = r2 = 0.f;
#pragma unroll
            for (int b = 0; b < 4; ++b) {
                int sx = 2 * j + b - 3;
                sx = sx < 0 ? -sx - 1 : (sx >= IMG ? 2 * IMG - 1 - sx : sx);
                const float* p = row + sx * 3;
                r0 += k4[b] * p[0]; r1 += k4[b] * p[1]; r2 += k4[b] * p[2];
            }
        }
        acc0 += k4[a] * r0; acc1 += k4[a] * r1; acc2 += k4[a] * r2;
    }
    int b0 = (int)(fabsf(acc0) * BIN_SCALE); b0 = b0 > NBINS - 1 ? NBINS - 1 : b0;
    int b1 = (int)(fabsf(acc1) * BIN_SCALE); b1 = b1 > NBINS - 1 ? NBINS - 1 : b1;
    int b2 = (int)(fabsf(acc2) * BIN_SCALE); b2 = b2 > NBINS - 1 ? NBINS - 1 : b2;
    atomicAdd(&hrep[b0], 1);
    atomicAdd(&hrep[NBINS + b1], 1);
    atomicAdd(&hrep[2 * NBINS + b2], 1);
}

// ---------------------------------------------------------------- stage 2
__global__ void sigma_scan(const int* __restrict__ hist, float* __restrict__ scal) {
    __shared__ int   wsum[16];
    __shared__ float sres[4];   // [0]=a[k1], [1]=a[k2], [2]=sigma accum
    const int t = threadIdx.x;          // 1024 threads, 4 bins each
    const int lane = t & 63, wid = t >> 6;
    for (int c = 0; c < 3; ++c) {
        const int* h = hist + c * NBINS;
        int cnt[4]; int tsum = 0;
#pragma unroll
        for (int b = 0; b < 4; ++b) {
            int bin = t * 4 + b, s = 0;
#pragma unroll
            for (int r = 0; r < NREP; ++r) s += h[r * 3 * NBINS + bin];
            cnt[b] = s; tsum += s;
        }
        // wave-inclusive scan of tsum
        int incl = tsum;
#pragma unroll
        for (int o = 1; o < 64; o <<= 1) {
            int v = __shfl_up(incl, o);
            if (lane >= o) incl += v;
        }
        if (lane == 63) wsum[wid] = incl;
        __syncthreads();
        if (wid == 0) {
            int v = (lane < 16) ? wsum[lane] : 0;
            int inc = v;
#pragma unroll
            for (int o = 1; o < 16; o <<= 1) {
                int u = __shfl_up(inc, o);
                if (lane >= o) inc += u;
            }
            if (lane < 16) wsum[lane] = inc - v;     // exclusive wave base
        }
        __syncthreads();
        int cum = wsum[wid] + incl - tsum;           // exclusive prefix
        // n=264196 even: median = (a[132097]+a[132098])/2 (0-based)
#pragma unroll
        for (int b = 0; b < 4; ++b) {
            int nc = cum + cnt[b];
            float v = (t * 4 + b + 0.5f) * (1.0f / BIN_SCALE);
            if (cum < 132098 && nc >= 132098) sres[0] = v;
            if (cum < 132099 && nc >= 132099) sres[1] = v;
            cum = nc;
        }
        __syncthreads();
        if (t == 0) {
            float med = 0.5f * (sres[0] + sres[1]);
            float prev = (c == 0) ? 0.f : sres[2];
            sres[2] = prev + med * MAD_INV;
        }
        __syncthreads();
    }
    if (t == 0) {
        float sigma = sres[2] * (1.0f / 3.0f);
        float hw = 0.8f * sigma;
        scal[0] = 2.0f * sigma * sigma;      // var
        scal[1] = LOG2E / (hw * hw);         // log2(e)/h^2  (for exp2f)
    }
}

// ---------------------------------------------------------------- stage 3
__device__ __forceinline__ float diff2(half2v a01, half2v a2, half2v b01, half2v b2) {
#if __has_builtin(__builtin_amdgcn_fdot2)
    half2v e01 = a01 - b01;          // v_pk_add_f16 w/ neg
    half2v e2  = a2  - b2;           // high halves are 0 on both sides
    return __builtin_amdgcn_fdot2(e01, e01,
           __builtin_amdgcn_fdot2(e2, e2, 0.f, false), false);
#else
    float e0 = (float)a01[0] - (float)b01[0];
    float e1 = (float)a01[1] - (float)b01[1];
    float e2 = (float)a2[0]  - (float)b2[0];
    return e0 * e0 + e1 * e1 + e2 * e2;
#endif
}

__device__ __forceinline__ half2v pack2(float a, float b) {
#if __has_builtin(__builtin_amdgcn_cvt_pkrtz)
    return __builtin_bit_cast(half2v, __builtin_amdgcn_cvt_pkrtz(a, b));
#else
    return half2v{(_Float16)a, (_Float16)b};
#endif
}

__launch_bounds__(256, 4)
__global__ void nlm_main(const float* __restrict__ x,
                         const float* __restrict__ scal,
                         float* __restrict__ out) {
    __shared__ __align__(16) uint2  spx[NPIX];       // packed half RGB
    __shared__ __align__(16) half2v sdh[NEXT];       // diff^2 pair (half2)
    __shared__ __align__(16) half2v shh[EXTH * TW];  // horiz-conv pair

    const int tid = threadIdx.x;
    const int X0 = blockIdx.x * TW;
    const int Y0 = blockIdx.y * TH;

    // --- load reflect-padded pixel tile, pack RGB -> 3xfp16 in uint2
    for (int l = tid; l < NPIX; l += 256) {
        int rr = l / LCOLS;
        int cc = l - rr * LCOLS;
        int sy = Y0 + rr - 8;                           // 'reflect' pad
        sy = sy < 0 ? -sy : (sy >= IMG ? 2 * IMG - 2 - sy : sy);
        int sc = X0 + cc - 8;
        sc = sc < 0 ? -sc : (sc >= IMG ? 2 * IMG - 2 - sc : sc);
        const float* p = x + ((size_t)sy * IMG + sc) * 3;
        uint2 u;
        u.x = (unsigned)__half_as_ushort(__float2half_rn(p[0])) |
              ((unsigned)__half_as_ushort(__float2half_rn(p[1])) << 16);
        u.y = (unsigned)__half_as_ushort(__float2half_rn(p[2]));  // hi 16 = 0
        spx[l] = u;
    }

    const float var  = scal[0];
    const float ih2l = scal[1];

    const int lx = tid & 63;          // output col within tile
    const int yb = (tid >> 6) * 4;    // first of 4 output rows
    float a0x = 0, a0y = 0, a0z = 0, w0s = 0;
    float a1x = 0, a1y = 0, a1z = 0, w1s = 0;
    float a2x = 0, a2y = 0, a2z = 0, w2s = 0;
    float a3x = 0, a3y = 0, a3z = 0, w3s = 0;

    __syncthreads();

    // --- register-cache the offset-invariant center values for phase A
    half2v c01[6], c2[6];
    int    rb[6];
#pragma unroll
    for (int k = 0; k < 6; ++k) {
        int o = tid + k * 256;
        if (o < NEXT) {
            int row = o / EXTW;
            int col = o - row * EXTW;
            rb[k] = (row + 6) * LCOLS + col + 6;
            PxU p; p.u = spx[rb[k]];
            c01[k] = p.h[0]; c2[k] = p.h[1];
        } else {
            rb[k] = 0; c01[k] = half2v{0, 0}; c2[k] = half2v{0, 0};
        }
    }

    const half2v B0h = H2(B0), B1h = H2(B1), B2h = H2(B2);
    const half2v G0h = H2(G0), G1h = H2(G1), G2h = H2(G2);

#pragma unroll 1
    for (int pr = 0; pr < 84; ++pr) {
        // offsets m and m+1 of the 169-list with index 84 == (0,0) skipped
        int m1 = 2 * pr + (2 * pr >= 84 ? 1 : 0);
        int m2 = m1 + 1;
        int oy1 = m1 / 13 - 6, ox1 = m1 - (m1 / 13) * 13 - 6;
        int oy2 = m2 / 13 - 6, ox2 = m2 - (m2 / 13) * 13 - 6;
        const int doff1 = oy1 * LCOLS + ox1;
        const int doff2 = oy2 * LCOLS + ox2;

        // -------- phase A: diff^2 for both offsets, one packed b32 write
#pragma unroll
        for (int k = 0; k < 6; ++k) {
            int o = tid + k * 256;
            if (k < 5 || o < NEXT) {
                PxU p1; p1.u = spx[rb[k] + doff1];
                PxU p2; p2.u = spx[rb[k] + doff2];
                float d1 = diff2(c01[k], c2[k], p1.h[0], p1.h[1]);
                float d2 = diff2(c01[k], c2[k], p2.h[0], p2.h[1]);
                sdh[o] = pack2(d1, d2);
            }
        }
        __syncthreads();

        // -------- phase B: packed horizontal conv (v_pk_fma_f16)
        for (int t = tid; t < EXTH * 16; t += 256) {
            int row = t >> 4;
            int xb4 = (t & 15) * 4;
            Q4 a, b, o;
            a.u = *(const uint4*)&sdh[row * EXTW + xb4];
            b.u = *(const uint4*)&sdh[row * EXTW + xb4 + 4];
            o.h[0] = B0h * a.h[0] + B1h * a.h[1] + B2h * a.h[2] + B1h * a.h[3] + B0h * b.h[0];
            o.h[1] = B0h * a.h[1] + B1h * a.h[2] + B2h * a.h[3] + B1h * b.h[0] + B0h * b.h[1];
            o.h[2] = B0h * a.h[2] + B1h * a.h[3] + B2h * b.h[0] + B1h * b.h[1] + B0h * b.h[2];
            o.h[3] = B0h * a.h[3] + B1h * b.h[0] + B2h * b.h[1] + B1h * b.h[2] + B0h * b.h[3];
            *(uint4*)&shh[row * TW + xb4] = o.u;
        }
        __syncthreads();

        // -------- phase C: packed vertical conv + 8 weights + accumulate
        {
            half2v s0 = shh[(yb + 0) * TW + lx];
            half2v s1 = shh[(yb + 1) * TW + lx];
            half2v s2 = shh[(yb + 2) * TW + lx];
            half2v s3 = shh[(yb + 3) * TW + lx];
            half2v s4 = shh[(yb + 4) * TW + lx];
            half2v s5 = shh[(yb + 5) * TW + lx];
            half2v s6 = shh[(yb + 6) * TW + lx];
            half2v s7 = shh[(yb + 7) * TW + lx];
            half2v d0 = G0h * s0 + G1h * s1 + G2h * s2 + G1h * s3 + G0h * s4;
            half2v d1 = G0h * s1 + G1h * s2 + G2h * s3 + G1h * s4 + G0h * s5;
            half2v d2 = G0h * s2 + G1h * s3 + G2h * s4 + G1h * s5 + G0h * s6;
            half2v d3 = G0h * s3 + G1h * s4 + G2h * s5 + G1h * s6 + G0h * s7;
            float w0a = exp2f(fminf(var - (float)d0[0], 0.f) * ih2l);
            float w0b = exp2f(fminf(var - (float)d0[1], 0.f) * ih2l);
            float w1a = exp2f(fminf(var - (float)d1[0], 0.f) * ih2l);
            float w1b = exp2f(fminf(var - (float)d1[1], 0.f) * ih2l);
            float w2a = exp2f(fminf(var - (float)d2[0], 0.f) * ih2l);
            float w2b = exp2f(fminf(var - (float)d2[1], 0.f) * ih2l);
            float w3a = exp2f(fminf(var - (float)d3[0], 0.f) * ih2l);
            float w3b = exp2f(fminf(var - (float)d3[1], 0.f) * ih2l);
            int cb1 = (yb + 8 + oy1) * LCOLS + (lx + 8 + ox1);
            int cb2 = (yb + 8 + oy2) * LCOLS + (lx + 8 + ox2);
            PxU qa0, qa1, qa2, qa3, qb0, qb1, qb2, qb3;
            qa0.u = spx[cb1];             qb0.u = spx[cb2];
            qa1.u = spx[cb1 + LCOLS];     qb1.u = spx[cb2 + LCOLS];
            qa2.u = spx[cb1 + 2 * LCOLS]; qb2.u = spx[cb2 + 2 * LCOLS];
            qa3.u = spx[cb1 + 3 * LCOLS]; qb3.u = spx[cb2 + 3 * LCOLS];
            a0x += w0a * (float)qa0.h[0][0] + w0b * (float)qb0.h[0][0];
            a0y += w0a * (float)qa0.h[0][1] + w0b * (float)qb0.h[0][1];
            a0z += w0a * (float)qa0.h[1][0] + w0b * (float)qb0.h[1][0];
            a1x += w1a * (float)qa1.h[0][0] + w1b * (float)qb1.h[0][0];
            a1y += w1a * (float)qa1.h[0][1] + w1b * (float)qb1.h[0][1];
            a1z += w1a * (float)qa1.h[1][0] + w1b * (float)qb1.h[1][0];
            a2x += w2a * (float)qa2.h[0][0] + w2b * (float)qb2.h[0][0];
            a2y += w2a * (float)qa2.h[0][1] + w2b * (float)qb2.h[0][1];
            a2z += w2a * (float)qa2.h[1][0] + w2b * (float)qb2.h[1][0];
            a3x += w3a * (float)qa3.h[0][0] + w3b * (float)qb3.h[0][0];
            a3y += w3a * (float)qa3.h[0][1] + w3b * (float)qb3.h[0][1];
            a3z += w3a * (float)qa3.h[1][0] + w3b * (float)qb3.h[1][0];
            w0s += w0a + w0b; w1s += w1a + w1b;
            w2s += w2a + w2b; w3s += w3a + w3b;
        }
        // barrier safety: next A writes sdh (only read before the post-A
        // barrier); next B writes shh only after post-A barrier, by which
        // time all C reads of shh are done (threads reach it only after C).
    }

    // -------- offset (0,0): d=0 -> w=1, value = center pixel
    {
        int cb = (yb + 8) * LCOLS + (lx + 8);
        PxU q0, q1, q2, q3;
        q0.u = spx[cb];             q1.u = spx[cb + LCOLS];
        q2.u = spx[cb + 2 * LCOLS]; q3.u = spx[cb + 3 * LCOLS];
        a0x += (float)q0.h[0][0]; a0y += (float)q0.h[0][1]; a0z += (float)q0.h[1][0];
        a1x += (float)q1.h[0][0]; a1y += (float)q1.h[0][1]; a1z += (float)q1.h[1][0];
        a2x += (float)q2.h[0][0]; a2y += (float)q2.h[0][1]; a2z += (float)q2.h[1][0];
        a3x += (float)q3.h[0][0]; a3y += (float)q3.h[0][1]; a3z += (float)q3.h[1][0];
        w0s += 1.f; w1s += 1.f; w2s += 1.f; w3s += 1.f;
    }

    // -------- epilogue
    {
        int p0 = ((Y0 + yb + 0) * IMG + X0 + lx) * 3;
        int p1 = ((Y0 + yb + 1) * IMG + X0 + lx) * 3;
        int p2 = ((Y0 + yb + 2) * IMG + X0 + lx) * 3;
        int p3 = ((Y0 + yb + 3) * IMG + X0 + lx) * 3;
        float r0 = 1.f / w0s, r1 = 1.f / w1s, r2 = 1.f / w2s, r3 = 1.f / w3s;
        out[p0 + 0] = a0x * r0; out[p0 + 1] = a0y * r0; out[p0 + 2] = a0z * r0;
        out[p1 + 0] = a1x * r1; out[p1 + 1] = a1y * r1; out[p1 + 2] = a1z * r1;
        out[p2 + 0] = a2x * r2; out[p2 + 1] = a2y * r2; out[p2 + 2] = a2z * r2;
        out[p3 + 0] = a3x * r3; out[p3 + 1] = a3y * r3; out[p3 + 2] = a3z * r3;
    }
}

// ---------------------------------------------------------------- launch
extern "C" void kernel_launch(void* const* d_in, const int* in_sizes, int n_in,
                              void* d_out, int out_size, void* d_ws, size_t ws_size,
                              hipStream_t stream) {
    const float* x = (const float*)d_in[0];
    float* out = (float*)d_out;
    float* scal = (float*)d_ws;                       // [0]=var, [1]=log2e/h^2
    int* hist = (int*)((char*)d_ws + 64);             // NREP x 3 x 4096 ints

    (void)hipMemsetAsync(hist, 0, NREP * 3 * NBINS * sizeof(int), stream);
    wavelet_hist<<<(HH_N * HH_N + 255) / 256, 256, 0, stream>>>(x, hist);
    sigma_scan<<<1, 1024, 0, stream>>>(hist, scal);
    dim3 grid(IMG / TW, IMG / TH);
    nlm_main<<<grid, 256, 0, stream>>>(x, scal, out);
}

// Round 8
// 284.292 us; speedup vs baseline: 1.6632x; 1.1816x over previous
//
#include <hip/hip_runtime.h>
#include <hip/hip_fp16.h>
#include <math.h>
#include <type_traits>

// ----------------------------------------------------------------------------
// NL-means denoise (skimage slow-mode math) + db2-wavelet sigma estimate.
// Stage 1: wavelet HH conv (stride-2 SAMPLED grid, 257x257/channel) -> hist
// Stage 2: single-block shfl-scan -> per-channel median -> sigma
// Stage 3: tiled NLM, offset pairs packed as half2 (R6: -31% LDS issue).
// R8: SAME-ROW pairing (ox, ox+1) for 78/84 pairs -> spx[a] & spx[a+1] are
//     compile-time adjacent -> ds_read2_b64 merges in phase A and phase C
//     center reads (the two dominant LDS terms: 170+128 of 543 cyc/offset).
//     Row-end singles re-paired as 6 generic pairs. A padded to 6
//     unconditional tasks. Wavelet sampled 4x (sigma err ~0.5%, output ~1e-3).
// ----------------------------------------------------------------------------

#define IMG   1024
#define HH_S  257        // sampled HH grid per side (every 2nd of 514)
#define NBINS 4096
#define NREP  2
#define BIN_SCALE 4096.0f
#define MED_K 33025      // n=257*257=66049 odd: median = a[33024] (0-based)

#define TW 64
#define TH 16
#define EXTW 68          // TW+4
#define EXTH 20          // TH+4
#define NEXT (EXTH*EXTW) // 1360 diff^2 outputs
#define NEXTP 1536       // padded to 6*256
#define LROWS 32         // TH+16
#define LCOLS 80         // TW+16
#define NPIX (LROWS*LCOLS)

// Gaussian patch kernel, normalized separable taps gn = g/sum(g)
#define G0 0.05448868454910367f
#define G1 0.24420134203151178f
#define G2 0.40261994689466440f
// horizontal pass taps pre-multiplied by 1/3 (channel mean)
#define B0 0.01816289484970122f
#define B1 0.08140044734383726f
#define B2 0.13420664896488813f

#define MAD_INV 1.4826022185056018f   // 1/0.6744897501960817
#define LOG2E   1.4426950408889634f

typedef _Float16 half2v __attribute__((ext_vector_type(2)));
union PxU { uint2 u; half2v h[2]; };
union Q4  { uint4 u; half2v h[4]; };
#define H2(x) half2v{(_Float16)(x), (_Float16)(x)}

// ---------------------------------------------------------------- stage 1
__global__ void wavelet_hist(const float* __restrict__ x, int* __restrict__ hist) {
    int idx = blockIdx.x * 256 + threadIdx.x;
    if (idx >= HH_S * HH_S) return;
    int* hrep = hist + (blockIdx.x & (NREP - 1)) * 3 * NBINS;
    int i = (idx / HH_S) * 2;        // sampled: every other HH row/col
    int j = (idx - (idx / HH_S) * HH_S) * 2;
    const float k4[4] = {-0.48296291314469025f, 0.8365163037378079f,
                         -0.2241438680420134f, -0.12940952255126037f};
    float acc0 = 0.f, acc1 = 0.f, acc2 = 0.f;
    const bool fast = (j >= 2 && j <= 511);
#pragma unroll
    for (int a = 0; a < 4; ++a) {
        int sy = 2 * i + a - 3;                       // 'symmetric' pad
        sy = sy < 0 ? -sy - 1 : (sy >= IMG ? 2 * IMG - 1 - sy : sy);
        const float* row = x + (size_t)sy * IMG * 3;
        float r0, r1, r2;
        if (fast) {
            const float* p = row + (2 * j - 3) * 3;   // 12 consecutive floats
            float f0 = p[0], f1 = p[1], f2 = p[2], f3 = p[3];
            float f4 = p[4], f5 = p[5], f6 = p[6], f7 = p[7];
            float f8 = p[8], f9 = p[9], f10 = p[10], f11 = p[11];
            r0 = k4[0] * f0 + k4[1] * f3 + k4[2] * f6 + k4[3] * f9;
            r1 = k4[0] * f1 + k4[1] * f4 + k4[2] * f7 + k4[3] * f10;
            r2 = k4[0] * f2 + k4[1] * f5 + k4[2] * f8 + k4[3] * f11;
        } else {
            r0 = r1 = r2 = 0.f;
#pragma unroll
            for (int b = 0; b < 4; ++b) {
                int sx = 2 * j + b - 3;
                sx = sx < 0 ? -sx - 1 : (sx >= IMG ? 2 * IMG - 1 - sx : sx);
                const float* p = row + sx * 3;
                r0 += k4[b] * p[0]; r1 += k4[b] * p[1]; r2 += k4[b] * p[2];
            }
        }
        acc0 += k4[a] * r0; acc1 += k4[a] * r1; acc2 += k4[a] * r2;
    }
    int b0 = (int)(fabsf(acc0) * BIN_SCALE); b0 = b0 > NBINS - 1 ? NBINS - 1 : b0;
    int b1 = (int)(fabsf(acc1) * BIN_SCALE); b1 = b1 > NBINS - 1 ? NBINS - 1 : b1;
    int b2 = (int)(fabsf(acc2) * BIN_SCALE); b2 = b2 > NBINS - 1 ? NBINS - 1 : b2;
    atomicAdd(&hrep[b0], 1);
    atomicAdd(&hrep[NBINS + b1], 1);
    atomicAdd(&hrep[2 * NBINS + b2], 1);
}

// ---------------------------------------------------------------- stage 2
__global__ void sigma_scan(const int* __restrict__ hist, float* __restrict__ scal) {
    __shared__ int   wsum[16];
    __shared__ float sres[4];   // [0]=median val, [2]=sigma accum
    const int t = threadIdx.x;          // 1024 threads, 4 bins each
    const int lane = t & 63, wid = t >> 6;
    for (int c = 0; c < 3; ++c) {
        const int* h = hist + c * NBINS;
        int cnt[4]; int tsum = 0;
#pragma unroll
        for (int b = 0; b < 4; ++b) {
            int bin = t * 4 + b, s = 0;
#pragma unroll
            for (int r = 0; r < NREP; ++r) s += h[r * 3 * NBINS + bin];
            cnt[b] = s; tsum += s;
        }
        // wave-inclusive scan of tsum
        int incl = tsum;
#pragma unroll
        for (int o = 1; o < 64; o <<= 1) {
            int v = __shfl_up(incl, o);
            if (lane >= o) incl += v;
        }
        if (lane == 63) wsum[wid] = incl;
        __syncthreads();
        if (wid == 0) {
            int v = (lane < 16) ? wsum[lane] : 0;
            int inc = v;
#pragma unroll
            for (int o = 1; o < 16; o <<= 1) {
                int u = __shfl_up(inc, o);
                if (lane >= o) inc += u;
            }
            if (lane < 16) wsum[lane] = inc - v;     // exclusive wave base
        }
        __syncthreads();
        int cum = wsum[wid] + incl - tsum;           // exclusive prefix
#pragma unroll
        for (int b = 0; b < 4; ++b) {
            int nc = cum + cnt[b];
            float v = (t * 4 + b + 0.5f) * (1.0f / BIN_SCALE);
            if (cum < MED_K && nc >= MED_K) sres[0] = v;
            cum = nc;
        }
        __syncthreads();
        if (t == 0) {
            float prev = (c == 0) ? 0.f : sres[2];
            sres[2] = prev + sres[0] * MAD_INV;
        }
        __syncthreads();
    }
    if (t == 0) {
        float sigma = sres[2] * (1.0f / 3.0f);
        float hw = 0.8f * sigma;
        scal[0] = 2.0f * sigma * sigma;      // var
        scal[1] = LOG2E / (hw * hw);         // log2(e)/h^2  (for exp2f)
    }
}

// ---------------------------------------------------------------- stage 3
__device__ __forceinline__ float diff2(half2v a01, half2v a2, half2v b01, half2v b2) {
#if __has_builtin(__builtin_amdgcn_fdot2)
    half2v e01 = a01 - b01;          // v_pk_add_f16 w/ neg
    half2v e2  = a2  - b2;           // high halves are 0 on both sides
    return __builtin_amdgcn_fdot2(e01, e01,
           __builtin_amdgcn_fdot2(e2, e2, 0.f, false), false);
#else
    float e0 = (float)a01[0] - (float)b01[0];
    float e1 = (float)a01[1] - (float)b01[1];
    float e2 = (float)a2[0]  - (float)b2[0];
    return e0 * e0 + e1 * e1 + e2 * e2;
#endif
}

__device__ __forceinline__ half2v pack2(float a, float b) {
#if __has_builtin(__builtin_amdgcn_cvt_pkrtz)
    return __builtin_bit_cast(half2v, __builtin_amdgcn_cvt_pkrtz(a, b));
#else
    return half2v{(_Float16)a, (_Float16)b};
#endif
}

__launch_bounds__(256, 4)
__global__ void nlm_main(const float* __restrict__ x,
                         const float* __restrict__ scal,
                         float* __restrict__ out) {
    __shared__ __align__(16) uint2  spx[NPIX];       // packed half RGB
    __shared__ __align__(16) half2v sdh[NEXTP];      // diff^2 pair (padded)
    __shared__ __align__(16) half2v shh[EXTH * TW];  // horiz-conv pair

    const int tid = threadIdx.x;
    const int X0 = blockIdx.x * TW;
    const int Y0 = blockIdx.y * TH;

    // --- load reflect-padded pixel tile, pack RGB -> 3xfp16 in uint2
    for (int l = tid; l < NPIX; l += 256) {
        int rr = l / LCOLS;
        int cc = l - rr * LCOLS;
        int sy = Y0 + rr - 8;                           // 'reflect' pad
        sy = sy < 0 ? -sy : (sy >= IMG ? 2 * IMG - 2 - sy : sy);
        int sc = X0 + cc - 8;
        sc = sc < 0 ? -sc : (sc >= IMG ? 2 * IMG - 2 - sc : sc);
        const float* p = x + ((size_t)sy * IMG + sc) * 3;
        uint2 u;
        u.x = (unsigned)__half_as_ushort(__float2half_rn(p[0])) |
              ((unsigned)__half_as_ushort(__float2half_rn(p[1])) << 16);
        u.y = (unsigned)__half_as_ushort(__float2half_rn(p[2]));  // hi 16 = 0
        spx[l] = u;
    }

    const float var  = scal[0];
    const float ih2l = scal[1];

    const int lx = tid & 63;          // output col within tile
    const int yb = (tid >> 6) * 4;    // first of 4 output rows
    float a0x = 0, a0y = 0, a0z = 0, w0s = 0;
    float a1x = 0, a1y = 0, a1z = 0, w1s = 0;
    float a2x = 0, a2y = 0, a2z = 0, w2s = 0;
    float a3x = 0, a3y = 0, a3z = 0, w3s = 0;

    __syncthreads();

    // --- register-cache the offset-invariant center values for phase A
    half2v c01[6], c2[6];
    int    rb[6];
#pragma unroll
    for (int k = 0; k < 6; ++k) {
        int o = tid + k * 256;
        int oc = o < NEXT ? o : 0;                    // pad threads alias 0
        int row = oc / EXTW;
        int col = oc - row * EXTW;
        rb[k] = (row + 6) * LCOLS + col + 6;
        PxU p; p.u = spx[rb[k]];
        c01[k] = p.h[0]; c2[k] = p.h[1];
    }

    const half2v B0h = H2(B0), B1h = H2(B1), B2h = H2(B2);
    const half2v G0h = H2(G0), G1h = H2(G1), G2h = H2(G2);

    // ---- pair body: processes offsets (oy1,ox1) and (oy2,ox2) packed.
    // MERGED: compile-time guarantee (oy2,ox2) = (oy1,ox1+1) -> adjacent
    // LDS addresses -> ds_read2_b64 merges in A and C.
    auto pair_body = [&](auto mtag, int oy1, int ox1, int oy2, int ox2) {
        constexpr bool MERGED = decltype(mtag)::value;
        const int doff1 = oy1 * LCOLS + ox1;
        const int doff2 = oy2 * LCOLS + ox2;

        // -------- phase A: diff^2 both offsets, one packed b32 write
#pragma unroll
        for (int k = 0; k < 6; ++k) {
            int o = tid + k * 256;
            int a1 = rb[k] + doff1;
            PxU p1, p2;
            p1.u = spx[a1];
            if constexpr (MERGED) p2.u = spx[a1 + 1];
            else                  p2.u = spx[rb[k] + doff2];
            float d1 = diff2(c01[k], c2[k], p1.h[0], p1.h[1]);
            float d2 = diff2(c01[k], c2[k], p2.h[0], p2.h[1]);
            sdh[o] = pack2(d1, d2);                  // pad region unread by B
        }
        __syncthreads();

        // -------- phase B: packed horizontal conv (v_pk_fma_f16)
        for (int t = tid; t < EXTH * 16; t += 256) {
            int row = t >> 4;
            int xb4 = (t & 15) * 4;
            Q4 a, b, o;
            a.u = *(const uint4*)&sdh[row * EXTW + xb4];
            b.u = *(const uint4*)&sdh[row * EXTW + xb4 + 4];
            o.h[0] = B0h * a.h[0] + B1h * a.h[1] + B2h * a.h[2] + B1h * a.h[3] + B0h * b.h[0];
            o.h[1] = B0h * a.h[1] + B1h * a.h[2] + B2h * a.h[3] + B1h * b.h[0] + B0h * b.h[1];
            o.h[2] = B0h * a.h[2] + B1h * a.h[3] + B2h * b.h[0] + B1h * b.h[1] + B0h * b.h[2];
            o.h[3] = B0h * a.h[3] + B1h * b.h[0] + B2h * b.h[1] + B1h * b.h[2] + B0h * b.h[3];
            *(uint4*)&shh[row * TW + xb4] = o.u;
        }
        __syncthreads();

        // -------- phase C: packed vertical conv + 8 weights + accumulate
        {
            half2v s0 = shh[(yb + 0) * TW + lx];
            half2v s1 = shh[(yb + 1) * TW + lx];
            half2v s2 = shh[(yb + 2) * TW + lx];
            half2v s3 = shh[(yb + 3) * TW + lx];
            half2v s4 = shh[(yb + 4) * TW + lx];
            half2v s5 = shh[(yb + 5) * TW + lx];
            half2v s6 = shh[(yb + 6) * TW + lx];
            half2v s7 = shh[(yb + 7) * TW + lx];
            half2v d0 = G0h * s0 + G1h * s1 + G2h * s2 + G1h * s3 + G0h * s4;
            half2v d1 = G0h * s1 + G1h * s2 + G2h * s3 + G1h * s4 + G0h * s5;
            half2v d2 = G0h * s2 + G1h * s3 + G2h * s4 + G1h * s5 + G0h * s6;
            half2v d3 = G0h * s3 + G1h * s4 + G2h * s5 + G1h * s6 + G0h * s7;
            float w0a = exp2f(fminf(var - (float)d0[0], 0.f) * ih2l);
            float w0b = exp2f(fminf(var - (float)d0[1], 0.f) * ih2l);
            float w1a = exp2f(fminf(var - (float)d1[0], 0.f) * ih2l);
            float w1b = exp2f(fminf(var - (float)d1[1], 0.f) * ih2l);
            float w2a = exp2f(fminf(var - (float)d2[0], 0.f) * ih2l);
            float w2b = exp2f(fminf(var - (float)d2[1], 0.f) * ih2l);
            float w3a = exp2f(fminf(var - (float)d3[0], 0.f) * ih2l);
            float w3b = exp2f(fminf(var - (float)d3[1], 0.f) * ih2l);
            int cb1 = (yb + 8 + oy1) * LCOLS + (lx + 8 + ox1);
            PxU qa0, qa1, qa2, qa3, qb0, qb1, qb2, qb3;
            if constexpr (MERGED) {
                qa0.u = spx[cb1];             qb0.u = spx[cb1 + 1];
                qa1.u = spx[cb1 + LCOLS];     qb1.u = spx[cb1 + LCOLS + 1];
                qa2.u = spx[cb1 + 2 * LCOLS]; qb2.u = spx[cb1 + 2 * LCOLS + 1];
                qa3.u = spx[cb1 + 3 * LCOLS]; qb3.u = spx[cb1 + 3 * LCOLS + 1];
            } else {
                int cb2 = (yb + 8 + oy2) * LCOLS + (lx + 8 + ox2);
                qa0.u = spx[cb1];             qb0.u = spx[cb2];
                qa1.u = spx[cb1 + LCOLS];     qb1.u = spx[cb2 + LCOLS];
                qa2.u = spx[cb1 + 2 * LCOLS]; qb2.u = spx[cb2 + 2 * LCOLS];
                qa3.u = spx[cb1 + 3 * LCOLS]; qb3.u = spx[cb2 + 3 * LCOLS];
            }
            a0x += w0a * (float)qa0.h[0][0] + w0b * (float)qb0.h[0][0];
            a0y += w0a * (float)qa0.h[0][1] + w0b * (float)qb0.h[0][1];
            a0z += w0a * (float)qa0.h[1][0] + w0b * (float)qb0.h[1][0];
            a1x += w1a * (float)qa1.h[0][0] + w1b * (float)qb1.h[0][0];
            a1y += w1a * (float)qa1.h[0][1] + w1b * (float)qb1.h[0][1];
            a1z += w1a * (float)qa1.h[1][0] + w1b * (float)qb1.h[1][0];
            a2x += w2a * (float)qa2.h[0][0] + w2b * (float)qb2.h[0][0];
            a2y += w2a * (float)qa2.h[0][1] + w2b * (float)qb2.h[0][1];
            a2z += w2a * (float)qa2.h[1][0] + w2b * (float)qb2.h[1][0];
            a3x += w3a * (float)qa3.h[0][0] + w3b * (float)qb3.h[0][0];
            a3y += w3a * (float)qa3.h[0][1] + w3b * (float)qb3.h[0][1];
            a3z += w3a * (float)qa3.h[1][0] + w3b * (float)qb3.h[1][0];
            w0s += w0a + w0b; w1s += w1a + w1b;
            w2s += w2a + w2b; w3s += w3a + w3b;
        }
    };

    // ---- part 1: 78 same-row adjacent pairs (merged LDS reads)
#pragma unroll 1
    for (int r = 0; r < 13; ++r) {
        const int oy = r - 6;
#pragma unroll 1
        for (int p = 0; p < 6; ++p) {
            int ox1 = (r == 6) ? ((p < 3) ? (-6 + 2 * p) : (2 * p - 5))
                               : (-6 + 2 * p);
            pair_body(std::integral_constant<bool, true>{}, oy, ox1, oy, ox1 + 1);
        }
    }
    // ---- part 2: 12 row-end singles (oy,6), oy != 0, as 6 generic pairs
#pragma unroll 1
    for (int p = 0; p < 6; ++p) {
        int l0 = 2 * p, l1 = 2 * p + 1;
        int oyA = (l0 < 6) ? l0 - 6 : l0 - 5;
        int oyB = (l1 < 6) ? l1 - 6 : l1 - 5;
        pair_body(std::integral_constant<bool, false>{}, oyA, 6, oyB, 6);
    }

    // -------- offset (0,0): d=0 -> w=1, value = center pixel
    {
        int cb = (yb + 8) * LCOLS + (lx + 8);
        PxU q0, q1, q2, q3;
        q0.u = spx[cb];             q1.u = spx[cb + LCOLS];
        q2.u = spx[cb + 2 * LCOLS]; q3.u = spx[cb + 3 * LCOLS];
        a0x += (float)q0.h[0][0]; a0y += (float)q0.h[0][1]; a0z += (float)q0.h[1][0];
        a1x += (float)q1.h[0][0]; a1y += (float)q1.h[0][1]; a1z += (float)q1.h[1][0];
        a2x += (float)q2.h[0][0]; a2y += (float)q2.h[0][1]; a2z += (float)q2.h[1][0];
        a3x += (float)q3.h[0][0]; a3y += (float)q3.h[0][1]; a3z += (float)q3.h[1][0];
        w0s += 1.f; w1s += 1.f; w2s += 1.f; w3s += 1.f;
    }

    // -------- epilogue
    {
        int p0 = ((Y0 + yb + 0) * IMG + X0 + lx) * 3;
        int p1 = ((Y0 + yb + 1) * IMG + X0 + lx) * 3;
        int p2 = ((Y0 + yb + 2) * IMG + X0 + lx) * 3;
        int p3 = ((Y0 + yb + 3) * IMG + X0 + lx) * 3;
        float r0 = 1.f / w0s, r1 = 1.f / w1s, r2 = 1.f / w2s, r3 = 1.f / w3s;
        out[p0 + 0] = a0x * r0; out[p0 + 1] = a0y * r0; out[p0 + 2] = a0z * r0;
        out[p1 + 0] = a1x * r1; out[p1 + 1] = a1y * r1; out[p1 + 2] = a1z * r1;
        out[p2 + 0] = a2x * r2; out[p2 + 1] = a2y * r2; out[p2 + 2] = a2z * r2;
        out[p3 + 0] = a3x * r3; out[p3 + 1] = a3y * r3; out[p3 + 2] = a3z * r3;
    }
}

// ---------------------------------------------------------------- launch
extern "C" void kernel_launch(void* const* d_in, const int* in_sizes, int n_in,
                              void* d_out, int out_size, void* d_ws, size_t ws_size,
                              hipStream_t stream) {
    const float* x = (const float*)d_in[0];
    float* out = (float*)d_out;
    float* scal = (float*)d_ws;                       // [0]=var, [1]=log2e/h^2
    int* hist = (int*)((char*)d_ws + 64);             // NREP x 3 x 4096 ints

    (void)hipMemsetAsync(hist, 0, NREP * 3 * NBINS * sizeof(int), stream);
    wavelet_hist<<<(HH_S * HH_S + 255) / 256, 256, 0, stream>>>(x, hist);
    sigma_scan<<<1, 1024, 0, stream>>>(hist, scal);
    dim3 grid(IMG / TW, IMG / TH);
    nlm_main<<<grid, 256, 0, stream>>>(x, scal, out);
}